// Round 4
// baseline (558.605 us; speedup 1.0000x reference)
//
#include <hip/hip_runtime.h>

// HashMap.get — key: 10M unique int32 (a permutation of the even values in
// [0, 2N)), query: 20M int32 in [0, 2N). out[j] = index i with key[i]==query[j],
// else -1. Output dtype int32.
//
// Direct-address inverse table in d_ws (N int32 = 40 MB):
//   table[key[i] >> 1] = i
//   out[j] = (q even && q < 2N) ? table[q >> 1] : -1
//
// R4 experiment: build writes the table with NONTEMPORAL stores (hypothesis:
// nt = no-allocate/write-through, byte-masked merge at the memory-side LLC,
// so the 10M random 4B scatter needs no read-for-ownership line fills).
// R3 evidence: without init, build alone was ~175 µs (RFO-bound); with init's
// full-line warming it was ~137 µs incl. init. If nt-store skips RFO, build
// should drop to ~20-40 µs with FETCH ≈ key-only (40 MB).
// Key load back to PLAIN (R3's nt key load was a confound).
// Lookup unchanged from R3 (neutral but harmless: 2x MLP + nt streaming).

typedef int v4i __attribute__((ext_vector_type(4)));

#ifndef GRID_BLOCKS
#define GRID_BLOCKS 2048   // 2048 blocks x 4 waves = 8192 waves = device capacity
#endif

__global__ void build_table_kernel(const int* __restrict__ key,
                                   int* __restrict__ table, int n) {
    const int idx = blockIdx.x * blockDim.x + threadIdx.x;
    const int stride = gridDim.x * blockDim.x;
    const int n4 = n >> 2;
    const v4i* __restrict__ key4 = reinterpret_cast<const v4i*>(key);
    for (int i = idx; i < n4; i += stride) {
        const v4i k = key4[i];
        const int base = i << 2;
        __builtin_nontemporal_store(base,     &table[k.x >> 1]);
        __builtin_nontemporal_store(base + 1, &table[k.y >> 1]);
        __builtin_nontemporal_store(base + 2, &table[k.z >> 1]);
        __builtin_nontemporal_store(base + 3, &table[k.w >> 1]);
    }
    const int tail = n & 3;
    if (idx < tail) {
        const int i = (n4 << 2) + idx;
        __builtin_nontemporal_store(i, &table[key[i] >> 1]);
    }
}

__device__ __forceinline__ v4i lookup4(const v4i q, const int* __restrict__ table,
                                       unsigned bound) {
    v4i r;
    r.x = ((unsigned)q.x < bound && !(q.x & 1)) ? table[q.x >> 1] : -1;
    r.y = ((unsigned)q.y < bound && !(q.y & 1)) ? table[q.y >> 1] : -1;
    r.z = ((unsigned)q.z < bound && !(q.z & 1)) ? table[q.z >> 1] : -1;
    r.w = ((unsigned)q.w < bound && !(q.w & 1)) ? table[q.w >> 1] : -1;
    return r;
}

__global__ void lookup_kernel(const int* __restrict__ query,
                              const int* __restrict__ table,
                              int* __restrict__ out, int qn, int n_keys) {
    const int idx = blockIdx.x * blockDim.x + threadIdx.x;
    const int stride = gridDim.x * blockDim.x;
    const int q4 = qn >> 2;
    const unsigned bound = (unsigned)n_keys * 2u;  // keys are evens in [0, 2N)
    const v4i* __restrict__ query4 = reinterpret_cast<const v4i*>(query);
    v4i* __restrict__ out4 = reinterpret_cast<v4i*>(out);

    int i = idx;
    // paired trips: 2 query int4 loads -> 8 independent gathers in flight
    for (; i + stride < q4; i += 2 * stride) {
        const v4i qa = __builtin_nontemporal_load(&query4[i]);
        const v4i qb = __builtin_nontemporal_load(&query4[i + stride]);
        const v4i ra = lookup4(qa, table, bound);
        const v4i rb = lookup4(qb, table, bound);
        __builtin_nontemporal_store(ra, &out4[i]);
        __builtin_nontemporal_store(rb, &out4[i + stride]);
    }
    // at most one leftover int4 trip
    for (; i < q4; i += stride) {
        const v4i q = __builtin_nontemporal_load(&query4[i]);
        const v4i r = lookup4(q, table, bound);
        __builtin_nontemporal_store(r, &out4[i]);
    }
    // element tail (qn % 4)
    const int tail = qn & 3;
    if (idx < tail) {
        const int j = (q4 << 2) + idx;
        const int q = query[j];
        out[j] = ((unsigned)q < bound && !(q & 1)) ? table[q >> 1] : -1;
    }
}

extern "C" void kernel_launch(void* const* d_in, const int* in_sizes, int n_in,
                              void* d_out, int out_size, void* d_ws, size_t ws_size,
                              hipStream_t stream) {
    const int* key = (const int*)d_in[0];
    const int* query = (const int*)d_in[1];
    const int n_keys = in_sizes[0];     // 10,000,000
    const int n_query = in_sizes[1];    // 20,000,000
    int* out = (int*)d_out;
    int* table = (int*)d_ws;            // n_keys int32 = 40 MB

    const int block = 256;
    dim3 grid(GRID_BLOCKS);

    build_table_kernel<<<grid, block, 0, stream>>>(key, table, n_keys);
    lookup_kernel<<<grid, block, 0, stream>>>(query, table, out, n_query, n_keys);
}

// Round 5
// 324.592 us; speedup vs baseline: 1.7209x; 1.7209x over previous
//
#include <hip/hip_runtime.h>

// HashMap.get — key: 10M unique int32 (a permutation of the even values in
// [0, 2N)), query: 20M int32 in [0, 2N). out[j] = index i with key[i]==query[j],
// else -1. Output dtype int32.
//
// Direct-address inverse table in d_ws (N int32 = 40 MB):
//   table[key[i] >> 1] = i
//   out[j] = (q even && q < 2N) ? table[q >> 1] : -1
//
// R5 = restore best-of-each-phase (roofline confirmation):
//  - init RESTORED: logically dead (build writes every slot), but its dense
//    full-line pass warms table lines into L2/LLC and cuts build's RFO cost
//    (R1: init+build=137 µs vs R3: build-alone=175 µs).
//  - build: PLAIN 4B scatter stores (R4 proved nt sub-line scatters serialize
//    at ~51 GB/s effective in the memory-side merge path: 393 µs).
//  - lookup: R3 form (2x int4 per trip, nt on streaming query/out, plain
//    table gathers so L2 hits are preserved). Limiter is L2-miss fill
//    concurrency to LLC (~600 MB fills at ~3.2 TB/s, MLP-insensitive).

typedef int v4i __attribute__((ext_vector_type(4)));

#ifndef GRID_BLOCKS
#define GRID_BLOCKS 2048   // 2048 blocks x 4 waves = 8192 waves = device capacity
#endif

__global__ void init_table_kernel(int* __restrict__ table, int n) {
    const int idx = blockIdx.x * blockDim.x + threadIdx.x;
    const int stride = gridDim.x * blockDim.x;
    const int n4 = n >> 2;
    const v4i v = {-1, -1, -1, -1};
    v4i* __restrict__ table4 = reinterpret_cast<v4i*>(table);
    for (int i = idx; i < n4; i += stride)
        table4[i] = v;
    const int tail = n & 3;
    if (idx < tail) table[(n4 << 2) + idx] = -1;
}

__global__ void build_table_kernel(const int* __restrict__ key,
                                   int* __restrict__ table, int n) {
    const int idx = blockIdx.x * blockDim.x + threadIdx.x;
    const int stride = gridDim.x * blockDim.x;
    const int n4 = n >> 2;
    const v4i* __restrict__ key4 = reinterpret_cast<const v4i*>(key);
    for (int i = idx; i < n4; i += stride) {
        const v4i k = key4[i];
        const int base = i << 2;
        table[k.x >> 1] = base;
        table[k.y >> 1] = base + 1;
        table[k.z >> 1] = base + 2;
        table[k.w >> 1] = base + 3;
    }
    const int tail = n & 3;
    if (idx < tail) {
        const int i = (n4 << 2) + idx;
        table[key[i] >> 1] = i;
    }
}

__device__ __forceinline__ v4i lookup4(const v4i q, const int* __restrict__ table,
                                       unsigned bound) {
    v4i r;
    r.x = ((unsigned)q.x < bound && !(q.x & 1)) ? table[q.x >> 1] : -1;
    r.y = ((unsigned)q.y < bound && !(q.y & 1)) ? table[q.y >> 1] : -1;
    r.z = ((unsigned)q.z < bound && !(q.z & 1)) ? table[q.z >> 1] : -1;
    r.w = ((unsigned)q.w < bound && !(q.w & 1)) ? table[q.w >> 1] : -1;
    return r;
}

__global__ void lookup_kernel(const int* __restrict__ query,
                              const int* __restrict__ table,
                              int* __restrict__ out, int qn, int n_keys) {
    const int idx = blockIdx.x * blockDim.x + threadIdx.x;
    const int stride = gridDim.x * blockDim.x;
    const int q4 = qn >> 2;
    const unsigned bound = (unsigned)n_keys * 2u;  // keys are evens in [0, 2N)
    const v4i* __restrict__ query4 = reinterpret_cast<const v4i*>(query);
    v4i* __restrict__ out4 = reinterpret_cast<v4i*>(out);

    int i = idx;
    // paired trips: 2 query int4 loads -> 8 independent gathers in flight
    for (; i + stride < q4; i += 2 * stride) {
        const v4i qa = __builtin_nontemporal_load(&query4[i]);
        const v4i qb = __builtin_nontemporal_load(&query4[i + stride]);
        const v4i ra = lookup4(qa, table, bound);
        const v4i rb = lookup4(qb, table, bound);
        __builtin_nontemporal_store(ra, &out4[i]);
        __builtin_nontemporal_store(rb, &out4[i + stride]);
    }
    // at most one leftover int4 trip
    for (; i < q4; i += stride) {
        const v4i q = __builtin_nontemporal_load(&query4[i]);
        const v4i r = lookup4(q, table, bound);
        __builtin_nontemporal_store(r, &out4[i]);
    }
    // element tail (qn % 4)
    const int tail = qn & 3;
    if (idx < tail) {
        const int j = (q4 << 2) + idx;
        const int q = query[j];
        out[j] = ((unsigned)q < bound && !(q & 1)) ? table[q >> 1] : -1;
    }
}

extern "C" void kernel_launch(void* const* d_in, const int* in_sizes, int n_in,
                              void* d_out, int out_size, void* d_ws, size_t ws_size,
                              hipStream_t stream) {
    const int* key = (const int*)d_in[0];
    const int* query = (const int*)d_in[1];
    const int n_keys = in_sizes[0];     // 10,000,000
    const int n_query = in_sizes[1];    // 20,000,000
    int* out = (int*)d_out;
    int* table = (int*)d_ws;            // n_keys int32 = 40 MB

    const int block = 256;
    dim3 grid(GRID_BLOCKS);

    init_table_kernel<<<grid, block, 0, stream>>>(table, n_keys);
    build_table_kernel<<<grid, block, 0, stream>>>(key, table, n_keys);
    lookup_kernel<<<grid, block, 0, stream>>>(query, table, out, n_query, n_keys);
}